// Round 5
// baseline (117.774 us; speedup 1.0000x reference)
//
#include <hip/hip_runtime.h>
#include <hip/hip_fp16.h>

// SuppLayer: out[b,c] = exp( sum_s x[b, cm[c,s]] * w[c,s] )
// B=4096, NCLASS=1000, NSUPP=64, NCHUNK=4096.
//
// Block = 1024 threads, BT=8 batch rows, 64 KB LDS tile of x rows stored
// TRANSPOSED as fp16 (slot idx = 16 B = 8 rows' values at column idx);
// one ds_read_b128 per (class,s) feeds 8 fp32 FMAs. One class per thread.
// cm/w pre-transposed into d_ws as [sg][class] -> coalesced 16B-stride loads.
//
// R4 lesson: VGPR=28 under launch_bounds(1024,8) cap 64 -> compiler
// serialized the gather (1 outstanding ds_read). R5: explicit 4-wide
// ds_read batching per sg group + software-pipelined cm/w prefetch,
// sized to fit the 64-VGPR budget (keeps 2 blocks/CU).

constexpr int B_       = 4096;
constexpr int NCLASS_  = 1000;
constexpr int NSUPP_   = 64;
constexpr int NCHUNK_  = 4096;
constexpr int BT       = 8;      // batch rows per block
constexpr int THREADS_ = 1024;
constexpr int SG_      = NSUPP_ / 4;            // 16 int4/float4 groups
constexpr size_t CMT_BYTES = (size_t)SG_ * NCLASS_ * 16;   // 256 KB
constexpr size_t WS_NEEDED = 2 * CMT_BYTES;                // 512 KB

// ---- pre-pass: cm,w (class-major) -> [sg][class] int4/float4 in ws ----
__global__ void transpose_cw_kernel(const int*   __restrict__ cm,
                                    const float* __restrict__ w,
                                    int4*        __restrict__ cmT,
                                    float4*      __restrict__ wT)
{
    const int tid = blockIdx.x * 256 + threadIdx.x;   // 0..31999
    if (tid < SG_ * NCLASS_) {
        const int sg = tid / NCLASS_, c = tid % NCLASS_;
        cmT[tid] = reinterpret_cast<const int4*>(cm)[c * SG_ + sg];
    } else if (tid < 2 * SG_ * NCLASS_) {
        const int k = tid - SG_ * NCLASS_;
        const int sg = k / NCLASS_, c = k % NCLASS_;
        wT[k] = reinterpret_cast<const float4*>(w)[c * SG_ + sg];
    }
}

template <bool USET>
__global__ __launch_bounds__(THREADS_, 8)
void supp_gather_kernel(const float* __restrict__ x,
                        const float* __restrict__ wSupp,
                        const int*   __restrict__ cmap,
                        const float4* __restrict__ wT,
                        const int4*   __restrict__ cmT,
                        float*       __restrict__ out)
{
    // tile[c*4 + k] = half2(row 2k, row 2k+1) at column c   (64 KB)
    __shared__ __align__(16) __half2 tile[NCHUNK_ * (BT / 2)];

    const int t  = threadIdx.x;
    const int rb = blockIdx.x * BT;   // first batch row of this tile

    // ---- stage: 8 rows of x -> fp16, transposed into LDS ----
    // thread t owns columns c = t + 1024p. Global: 4B coalesced.
    // LDS write: float4 at byte addr c*16 -> 16B lane stride, conflict-free.
    #pragma unroll
    for (int p = 0; p < NCHUNK_ / THREADS_; ++p) {   // 4 iterations
        const int c = t + THREADS_ * p;
        float v[BT];
        #pragma unroll
        for (int bi = 0; bi < BT; ++bi)
            v[bi] = x[(size_t)(rb + bi) * NCHUNK_ + c];
        __half2 h[BT / 2];
        #pragma unroll
        for (int k = 0; k < BT / 2; ++k)
            h[k] = __floats2half2_rn(v[2 * k], v[2 * k + 1]);
        *reinterpret_cast<float4*>(&tile[(size_t)c * 4]) =
            *reinterpret_cast<float4*>(h);
    }
    __syncthreads();

    // ---- gather: one class per thread, software-pipelined ----
    if (t < NCLASS_) {
        const int c = t;
        const float4* tile4 = reinterpret_cast<const float4*>(tile);
        float acc[BT] = {0.f, 0.f, 0.f, 0.f, 0.f, 0.f, 0.f, 0.f};

        int4   ci;
        float4 wf;
        if constexpr (USET) { ci = cmT[c];               wf = wT[c]; }
        else {
            ci = reinterpret_cast<const int4*>(cmap + c * NSUPP_)[0];
            wf = reinterpret_cast<const float4*>(wSupp + c * NSUPP_)[0];
        }

        for (int sg = 0; sg < SG_; ++sg) {
            // issue all 4 independent ds_read_b128 up front
            float4 d0 = tile4[ci.x];
            float4 d1 = tile4[ci.y];
            float4 d2 = tile4[ci.z];
            float4 d3 = tile4[ci.w];
            const float4 wv = wf;

            // prefetch next group's cm/w (L2 ~200cyc) past this group's math
            const int sgn = (sg + 1 < SG_) ? sg + 1 : SG_ - 1;
            if constexpr (USET) {
                ci = cmT[sgn * NCLASS_ + c];
                wf = wT [sgn * NCLASS_ + c];
            } else {
                ci = reinterpret_cast<const int4*>(cmap + c * NSUPP_)[sgn];
                wf = reinterpret_cast<const float4*>(wSupp + c * NSUPP_)[sgn];
            }

            const float4* dp[4] = {&d0, &d1, &d2, &d3};
            const float   ws4[4] = {wv.x, wv.y, wv.z, wv.w};
            #pragma unroll
            for (int j = 0; j < 4; ++j) {
                const __half2* h2 = reinterpret_cast<const __half2*>(dp[j]);
                #pragma unroll
                for (int k = 0; k < 4; ++k) {
                    const float2 f = __half22float2(h2[k]);
                    acc[2 * k]     = fmaf(f.x, ws4[j], acc[2 * k]);
                    acc[2 * k + 1] = fmaf(f.y, ws4[j], acc[2 * k + 1]);
                }
            }
        }
        #pragma unroll
        for (int bi = 0; bi < BT; ++bi)
            out[(size_t)(rb + bi) * NCLASS_ + c] = __expf(acc[bi]);
    }
}

extern "C" void kernel_launch(void* const* d_in, const int* in_sizes, int n_in,
                              void* d_out, int out_size, void* d_ws, size_t ws_size,
                              hipStream_t stream) {
    const float* x  = (const float*)d_in[0];   // (B, NCHUNK) fp32
    const float* w  = (const float*)d_in[1];   // (NCLASS, NSUPP) fp32
    const int*   cm = (const int*)d_in[2];     // (NCLASS, NSUPP) int32
    float*       o  = (float*)d_out;           // (B, NCLASS) fp32

    int4*   cmT = (int4*)d_ws;
    float4* wT  = (float4*)((char*)d_ws + CMT_BYTES);

    if (ws_size >= WS_NEEDED) {
        const int total = 2 * SG_ * NCLASS_;             // 32000 threads
        transpose_cw_kernel<<<dim3((total + 255) / 256), dim3(256), 0, stream>>>(
            cm, w, cmT, wT);
        supp_gather_kernel<true><<<dim3(B_ / BT), dim3(THREADS_), 0, stream>>>(
            x, w, cm, wT, cmT, o);
    } else {
        supp_gather_kernel<false><<<dim3(B_ / BT), dim3(THREADS_), 0, stream>>>(
            x, w, cm, wT, cmT, o);
    }
}

// Round 6
// 116.648 us; speedup vs baseline: 1.0097x; 1.0097x over previous
//
#include <hip/hip_runtime.h>
#include <hip/hip_fp16.h>

// SuppLayer: out[b,c] = exp( sum_s x[b, cm[c,s]] * w[c,s] )
// B=4096, NCLASS=1000, NSUPP=64, NCHUNK=4096.
//
// Persistent double-buffered structure (R6):
//  grid 256 x 1024 threads; block owns 16 rows = 2 tiles of BT=8.
//  LDS: 2 x 64 KB buffers (fp16, slot idx = 16 B = 8 rows at column idx).
//  Timeline: stage0 | barrier | gather0 (b128 LDS) || prefetch x(tile1)
//            | write buf1 | barrier | gather1.
//  The tile-1 HBM loads hide under tile-0's LDS gather -> pipes overlap.
// cm/w pre-transposed into d_ws as [sg][class] -> coalesced 16B-stride loads
// (R3/R4 lessons: compile-time path select; no dynamic branch in hot loop).

constexpr int B_       = 4096;
constexpr int NCLASS_  = 1000;
constexpr int NSUPP_   = 64;
constexpr int NCHUNK_  = 4096;
constexpr int BT       = 8;       // batch rows per tile
constexpr int TILES_   = 2;       // tiles per block
constexpr int THREADS_ = 1024;
constexpr int PCOLS_   = NCHUNK_ / THREADS_;    // 4 columns per thread
constexpr int SG_      = NSUPP_ / 4;            // 16 int4/float4 groups
constexpr size_t CMT_BYTES = (size_t)SG_ * NCLASS_ * 16;   // 256 KB
constexpr size_t WS_NEEDED = 2 * CMT_BYTES;                // 512 KB

// ---- pre-pass: cm,w (class-major) -> [sg][class] int4/float4 in ws ----
__global__ void transpose_cw_kernel(const int*   __restrict__ cm,
                                    const float* __restrict__ w,
                                    int4*        __restrict__ cmT,
                                    float4*      __restrict__ wT)
{
    const int tid = blockIdx.x * 256 + threadIdx.x;   // 0..31999
    if (tid < SG_ * NCLASS_) {
        const int sg = tid / NCLASS_, c = tid % NCLASS_;
        cmT[tid] = reinterpret_cast<const int4*>(cm)[c * SG_ + sg];
    } else if (tid < 2 * SG_ * NCLASS_) {
        const int k = tid - SG_ * NCLASS_;
        const int sg = k / NCLASS_, c = k % NCLASS_;
        wT[k] = reinterpret_cast<const float4*>(w)[c * SG_ + sg];
    }
}

template <bool USET>
__global__ __launch_bounds__(THREADS_, 4)
void supp_gather_kernel(const float* __restrict__ x,
                        const float* __restrict__ wSupp,
                        const int*   __restrict__ cmap,
                        const float4* __restrict__ wT,
                        const int4*   __restrict__ cmT,
                        float*       __restrict__ out)
{
    // buf[b][c*4 + k] = half2(row 2k, row 2k+1) at column c  (2 x 64 KB)
    __shared__ __align__(16) __half2 buf[2][NCHUNK_ * (BT / 2)];

    const int t  = threadIdx.x;
    const int rb = blockIdx.x * (BT * TILES_);   // first of 16 rows

    // ---- stage tile 0 ----
    #pragma unroll
    for (int p = 0; p < PCOLS_; ++p) {
        const int c = t + THREADS_ * p;
        float v[BT];
        #pragma unroll
        for (int bi = 0; bi < BT; ++bi)
            v[bi] = x[(size_t)(rb + bi) * NCHUNK_ + c];
        __half2 h[BT / 2];
        #pragma unroll
        for (int k = 0; k < BT / 2; ++k)
            h[k] = __floats2half2_rn(v[2 * k], v[2 * k + 1]);
        *reinterpret_cast<float4*>(&buf[0][(size_t)c * 4]) =
            *reinterpret_cast<float4*>(h);
    }
    __syncthreads();

    #pragma unroll
    for (int tile = 0; tile < TILES_; ++tile) {
        const int rbt = rb + tile * BT;

        // ---- prefetch next tile's x into registers (hides under gather) ----
        float vn[PCOLS_][BT];
        if (tile + 1 < TILES_) {
            #pragma unroll
            for (int p = 0; p < PCOLS_; ++p) {
                const int c = t + THREADS_ * p;
                #pragma unroll
                for (int bi = 0; bi < BT; ++bi)
                    vn[p][bi] = x[(size_t)(rbt + BT + bi) * NCHUNK_ + c];
            }
        }

        // ---- gather from buf[tile]: one class per thread ----
        if (t < NCLASS_) {
            const int c = t;
            const float4* tile4 = reinterpret_cast<const float4*>(buf[tile]);
            float acc[BT] = {0.f, 0.f, 0.f, 0.f, 0.f, 0.f, 0.f, 0.f};

            int4   ci;
            float4 wf;
            if constexpr (USET) { ci = cmT[c]; wf = wT[c]; }
            else {
                ci = reinterpret_cast<const int4*>(cmap + c * NSUPP_)[0];
                wf = reinterpret_cast<const float4*>(wSupp + c * NSUPP_)[0];
            }

            for (int sg = 0; sg < SG_; ++sg) {
                // 4 independent ds_read_b128 issued up front
                float4 d0 = tile4[ci.x];
                float4 d1 = tile4[ci.y];
                float4 d2 = tile4[ci.z];
                float4 d3 = tile4[ci.w];
                const float4 wv = wf;

                // prefetch next group's cm/w (L2) past this group's math
                const int sgn = (sg + 1 < SG_) ? sg + 1 : SG_ - 1;
                if constexpr (USET) {
                    ci = cmT[sgn * NCLASS_ + c];
                    wf = wT [sgn * NCLASS_ + c];
                } else {
                    ci = reinterpret_cast<const int4*>(cmap + c * NSUPP_)[sgn];
                    wf = reinterpret_cast<const float4*>(wSupp + c * NSUPP_)[sgn];
                }

                const float4* dp[4]  = {&d0, &d1, &d2, &d3};
                const float   ws4[4] = {wv.x, wv.y, wv.z, wv.w};
                #pragma unroll
                for (int j = 0; j < 4; ++j) {
                    const __half2* h2 = reinterpret_cast<const __half2*>(dp[j]);
                    #pragma unroll
                    for (int k = 0; k < 4; ++k) {
                        const float2 f = __half22float2(h2[k]);
                        acc[2 * k]     = fmaf(f.x, ws4[j], acc[2 * k]);
                        acc[2 * k + 1] = fmaf(f.y, ws4[j], acc[2 * k + 1]);
                    }
                }
            }
            #pragma unroll
            for (int bi = 0; bi < BT; ++bi)
                out[(size_t)(rbt + bi) * NCLASS_ + c] = __expf(acc[bi]);
        }

        // ---- write staged tile into the other buffer ----
        if (tile + 1 < TILES_) {
            #pragma unroll
            for (int p = 0; p < PCOLS_; ++p) {
                const int c = t + THREADS_ * p;
                __half2 h[BT / 2];
                #pragma unroll
                for (int k = 0; k < BT / 2; ++k)
                    h[k] = __floats2half2_rn(vn[p][2 * k], vn[p][2 * k + 1]);
                *reinterpret_cast<float4*>(&buf[tile + 1][(size_t)c * 4]) =
                    *reinterpret_cast<float4*>(h);
            }
            __syncthreads();
        }
    }
}

extern "C" void kernel_launch(void* const* d_in, const int* in_sizes, int n_in,
                              void* d_out, int out_size, void* d_ws, size_t ws_size,
                              hipStream_t stream) {
    const float* x  = (const float*)d_in[0];   // (B, NCHUNK) fp32
    const float* w  = (const float*)d_in[1];   // (NCLASS, NSUPP) fp32
    const int*   cm = (const int*)d_in[2];     // (NCLASS, NSUPP) int32
    float*       o  = (float*)d_out;           // (B, NCLASS) fp32

    int4*   cmT = (int4*)d_ws;
    float4* wT  = (float4*)((char*)d_ws + CMT_BYTES);

    const dim3 grid(B_ / (BT * TILES_));       // 256 blocks
    if (ws_size >= WS_NEEDED) {
        const int total = 2 * SG_ * NCLASS_;   // 32000 threads
        transpose_cw_kernel<<<dim3((total + 255) / 256), dim3(256), 0, stream>>>(
            cm, w, cmT, wT);
        supp_gather_kernel<true><<<grid, dim3(THREADS_), 0, stream>>>(
            x, w, cm, wT, cmT, o);
    } else {
        supp_gather_kernel<false><<<grid, dim3(THREADS_), 0, stream>>>(
            x, w, cm, wT, cmT, o);
    }
}